// Round 11
// baseline (544.872 us; speedup 1.0000x reference)
//
#include <hip/hip_runtime.h>
#include <hip/hip_bf16.h>
#include <stdint.h>

#define NB 8
#define NSEQ 1024
#define DIMM 768
#define NHEADS 12
#define DH 64
#define NQKV 2304
#define ALPHA_ 0.25f
#define SCALE_ 0.125f
#define EPS_ 1e-5f

typedef __bf16 bf16;
typedef bf16 bf16x8 __attribute__((ext_vector_type(8)));
typedef bf16 bf16x4 __attribute__((ext_vector_type(4)));
typedef float f32x4 __attribute__((ext_vector_type(4)));

#define MFMA16(a, b, c) __builtin_amdgcn_mfma_f32_16x16x32_bf16((a), (b), (c), 0, 0, 0)

static __device__ __forceinline__ void load_lds16(const void* gsrc, void* ldst) {
  __builtin_amdgcn_global_load_lds(
      (__attribute__((address_space(1))) void*)gsrc,
      (__attribute__((address_space(3))) void*)ldst, 16, 0, 0);
}

// lgkm-only barrier (in-flight global loads ride across)
#define BAR_LGKM()                                             \
  do {                                                         \
    __builtin_amdgcn_sched_barrier(0);                         \
    asm volatile("s_waitcnt lgkmcnt(0)" ::: "memory");         \
    __builtin_amdgcn_s_barrier();                              \
    __builtin_amdgcn_sched_barrier(0);                         \
  } while (0)

// LDS byte-offset swizzle (row stride ==0 mod 128B): XOR bits[6:4] with
// (row&7) ^ colbyte bits[9:7]. Preserves 16B alignment.
static __device__ __forceinline__ int swz(int row, int cb) {
  return cb ^ ((((row & 7) ^ ((cb >> 7) & 7)) << 4));
}

// ---------------- LayerNorm + bf16 cast: x(8192x768) -> xn bf16 ----------------
__global__ __launch_bounds__(256) void ln_kernel(
    const float* __restrict__ x, const float* __restrict__ gamma,
    const float* __restrict__ beta, bf16* __restrict__ xn) {
  const int row = blockIdx.x * 4 + (threadIdx.x >> 6);
  const int lane = threadIdx.x & 63;
  const float* xr = x + (size_t)row * DIMM;
  float4 v[3];
  float s = 0.f, s2 = 0.f;
#pragma unroll
  for (int c = 0; c < 3; ++c) {
    v[c] = *reinterpret_cast<const float4*>(xr + c * 256 + lane * 4);
    s += v[c].x + v[c].y + v[c].z + v[c].w;
    s2 += v[c].x * v[c].x + v[c].y * v[c].y + v[c].z * v[c].z + v[c].w * v[c].w;
  }
#pragma unroll
  for (int m = 1; m < 64; m <<= 1) {
    s += __shfl_xor(s, m);
    s2 += __shfl_xor(s2, m);
  }
  const float mu = s * (1.f / DIMM);
  const float rstd = rsqrtf(s2 * (1.f / DIMM) - mu * mu + EPS_);
#pragma unroll
  for (int c = 0; c < 3; ++c) {
    const float4 g4 = *reinterpret_cast<const float4*>(gamma + c * 256 + lane * 4);
    const float4 b4 = *reinterpret_cast<const float4*>(beta + c * 256 + lane * 4);
    bf16x4 o;
    o[0] = (bf16)((v[c].x - mu) * rstd * g4.x + b4.x);
    o[1] = (bf16)((v[c].y - mu) * rstd * g4.y + b4.y);
    o[2] = (bf16)((v[c].z - mu) * rstd * g4.z + b4.z);
    o[3] = (bf16)((v[c].w - mu) * rstd * g4.w + b4.w);
    *reinterpret_cast<bf16x4*>(xn + (size_t)row * DIMM + c * 256 + lane * 4) = o;
  }
}

// ------------- transpose + cast: f32 in[R][C] -> bf16 out[C][R] -------------
__global__ __launch_bounds__(256) void tcast_kernel(
    const float* __restrict__ in, bf16* __restrict__ out, int R, int C) {
  __shared__ float tile[32][33];
  const int tx = threadIdx.x & 31, ty = threadIdx.x >> 5;
  const int c0 = blockIdx.x * 32, r0 = blockIdx.y * 32;
#pragma unroll
  for (int i = ty; i < 32; i += 8)
    tile[i][tx] = in[(size_t)(r0 + i) * C + c0 + tx];
  __syncthreads();
#pragma unroll
  for (int i = ty; i < 32; i += 8)
    out[(size_t)(c0 + i) * R + r0 + tx] = (bf16)tile[tx][i];
}

// -------- QKV GEMM: xn(8192x768) @ wT(2304 cols x 768 k) -> q,k,vT bf16 --------
__global__ __launch_bounds__(256) void qkv_gemm(
    const bf16* __restrict__ xn, const bf16* __restrict__ wT,
    bf16* __restrict__ qb, bf16* __restrict__ kb, bf16* __restrict__ vt) {
  __shared__ __align__(16) bf16 As[128 * 32];
  __shared__ __align__(16) bf16 Bs[64 * 32];
  const int tid = threadIdx.x;
  const int wv = tid >> 6, l = tid & 63;
  const int l16 = l & 15, q4 = l >> 4;
  const int c0 = blockIdx.x * 64, row0 = blockIdx.y * 128;
  const int sr = tid >> 2, skk = (tid & 3) * 8;
  f32x4 acc0[4], acc1[4];
#pragma unroll
  for (int c = 0; c < 4; ++c) {
    acc0[c] = f32x4{0.f, 0.f, 0.f, 0.f};
    acc1[c] = f32x4{0.f, 0.f, 0.f, 0.f};
  }
  for (int k0 = 0; k0 < DIMM; k0 += 32) {
    __syncthreads();
    load_lds16(xn + (size_t)(row0 + sr) * DIMM + k0 + skk, As + tid * 8);
    load_lds16(xn + (size_t)(row0 + 64 + sr) * DIMM + k0 + skk, As + 2048 + tid * 8);
    load_lds16(wT + (size_t)(c0 + sr) * DIMM + k0 + skk, Bs + tid * 8);
    __syncthreads();
    const bf16x8 a0 = *reinterpret_cast<const bf16x8*>(&As[(wv * 32 + l16) * 32 + q4 * 8]);
    const bf16x8 a1 = *reinterpret_cast<const bf16x8*>(&As[(wv * 32 + 16 + l16) * 32 + q4 * 8]);
#pragma unroll
    for (int c = 0; c < 4; ++c) {
      const bf16x8 bb = *reinterpret_cast<const bf16x8*>(&Bs[(c * 16 + l16) * 32 + q4 * 8]);
      acc0[c] = MFMA16(a0, bb, acc0[c]);
      acc1[c] = MFMA16(a1, bb, acc1[c]);
    }
  }
  const int sect = c0 / DIMM;          // 0=q 1=k 2=v (uniform per block)
  const int head = (c0 % DIMM) >> 6;   // uniform per block
#pragma unroll
  for (int c = 0; c < 4; ++c) {
    const int dd = c * 16 + l16;
#pragma unroll
    for (int r = 0; r < 4; ++r) {
#pragma unroll
      for (int rsub = 0; rsub < 2; ++rsub) {
        const int gm = row0 + wv * 32 + rsub * 16 + q4 * 4 + r;
        const int b = gm >> 10, n = gm & 1023;
        const size_t bhh = (size_t)b * NHEADS + head;
        const float av = rsub ? acc1[c][r] : acc0[c][r];
        const bf16 val = (bf16)av;
        if (sect == 0)      qb[(bhh * NSEQ + n) * DH + dd] = val;
        else if (sect == 1) kb[(bhh * NSEQ + n) * DH + dd] = val;
        else                vt[(bhh * DH + dd) * NSEQ + n] = val;
      }
    }
  }
}

// -------- fused attention, chunked 3-phase, 5 blocks/CU pinned --------
// Block: 16 q-rows; j in 2 chunks of 512 with flash-style online rescale.
// launch_bounds(256,5): VGPR budget 102 -> compiler must NOT chase the
// LDS-implied 8 blocks (R9's spill failure mode). h prefetched into regs:
// chunk 0 before P1(0); chunk 1 issued inside P2(0) right after each row's
// h is consumed (in flight across P3(0)+BAR+P1(1)).
__global__ __launch_bounds__(256, 5) void attn_kernel(
    const bf16* __restrict__ qb, const bf16* __restrict__ kb,
    const bf16* __restrict__ vt, const float* __restrict__ h,
    float* __restrict__ blended, bf16* __restrict__ attn_out) {
  __shared__ __align__(16) char S_lds[16 * 1152];  // 18,432 B
  __shared__ __align__(16) float scl[16];
  __shared__ __align__(16) float lred[16];

  const int tid = threadIdx.x;
  const int wv = tid >> 6, l = tid & 63;
  const int l16 = l & 15, q4 = l >> 4;
  const int i0 = blockIdx.x * 16;
  const int bh = blockIdx.y;

  const float* hbase = h + ((size_t)bh << 20);
  float* bbase = blended + ((size_t)bh << 20);
  const bf16* kbase = kb + (size_t)bh * NSEQ * DH;
  const bf16* vbase = vt + (size_t)bh * DH * NSEQ;

  bf16x8 qT[2];
#pragma unroll
  for (int w2 = 0; w2 < 2; ++w2)
    qT[w2] = *reinterpret_cast<const bf16x8*>(
        qb + ((size_t)bh * NSEQ + i0 + l16) * DH + w2 * 32 + q4 * 8);

  // h prefetch registers: 4 rows x 2 halves = 32 VGPR
  f32x4 hr[4][2];
#pragma unroll
  for (int rr = 0; rr < 4; ++rr) {
    const float* hp = hbase + (size_t)(i0 + wv * 4 + rr) * NSEQ + l * 8;
    hr[rr][0] = *reinterpret_cast<const f32x4*>(hp);
    hr[rr][1] = *reinterpret_cast<const f32x4*>(hp + 4);
  }

  f32x4 acc[4];
#pragma unroll
  for (int kk = 0; kk < 4; ++kk) acc[kk] = f32x4{0.f, 0.f, 0.f, 0.f};
  float m_run[4], l_run[4];
#pragma unroll
  for (int r = 0; r < 4; ++r) { m_run[r] = -1e30f; l_run[r] = 0.f; }

#pragma unroll
  for (int c = 0; c < 2; ++c) {
    // ---- P1: S chunk -> LDS (wave strip = 128 cols x all 16 rows) ----
    {
      const bf16* kq = kbase + (size_t)(c * 512 + wv * 128 + l16) * DH + q4 * 8;
      char* srow_w = S_lds + l16 * 1152;
#pragma unroll
      for (int st = 0; st < 2; ++st) {
        f32x4 s[4];
#pragma unroll
        for (int js = 0; js < 4; ++js) s[js] = f32x4{0.f, 0.f, 0.f, 0.f};
#pragma unroll
        for (int js = 0; js < 4; ++js) {
#pragma unroll
          for (int w2 = 0; w2 < 2; ++w2) {
            const bf16x8 kf = *reinterpret_cast<const bf16x8*>(
                kq + (size_t)(st * 64 + js * 16) * DH + w2 * 32);
            s[js] = MFMA16(kf, qT[w2], s[js]);
          }
        }
#pragma unroll
        for (int js = 0; js < 4; ++js) {
          bf16x4 pk;
#pragma unroll
          for (int r = 0; r < 4; ++r) pk[r] = (bf16)(s[js][r] * (ALPHA_ * SCALE_));
          const int cb = (wv * 256 + st * 128 + js * 32 + q4 * 8);
          *reinterpret_cast<bf16x4*>(srow_w + swz(l16, cb)) = pk;
        }
      }
    }
    BAR_LGKM();  // S visible

    // ---- P2: stream 4 full rows; online softmax; P->LDS; h(c+1) reissue ----
#pragma unroll
    for (int rr = 0; rr < 4; ++rr) {
      const int row = wv * 4 + rr;
      char* srow = S_lds + row * 1152;
      const bf16x8 sv = *reinterpret_cast<const bf16x8*>(srow + swz(row, l * 16));
      float bl[8];
#pragma unroll
      for (int t = 0; t < 4; ++t) bl[t] = fmaf(0.75f, hr[rr][0][t], (float)sv[t]);
#pragma unroll
      for (int t = 0; t < 4; ++t) bl[4 + t] = fmaf(0.75f, hr[rr][1][t], (float)sv[4 + t]);
      // h consumed for this row: immediately issue next chunk's loads
      if (c == 0) {
        const float* hp = hbase + (size_t)(i0 + row) * NSEQ + 512 + l * 8;
        hr[rr][0] = *reinterpret_cast<const f32x4*>(hp);
        hr[rr][1] = *reinterpret_cast<const f32x4*>(hp + 4);
      }
      float* bp = bbase + (size_t)(i0 + row) * NSEQ + c * 512 + l * 8;
      f32x4 b0, b1;
#pragma unroll
      for (int t = 0; t < 4; ++t) { b0[t] = bl[t]; b1[t] = bl[4 + t]; }
      *reinterpret_cast<f32x4*>(bp) = b0;
      *reinterpret_cast<f32x4*>(bp + 4) = b1;
      float tm = bl[0];
#pragma unroll
      for (int t = 1; t < 8; ++t) tm = fmaxf(tm, bl[t]);
#pragma unroll
      for (int mm = 1; mm < 64; mm <<= 1) tm = fmaxf(tm, __shfl_xor(tm, mm));
      const float mnew = fmaxf(m_run[rr], tm);
      const float sc = __expf(m_run[rr] - mnew);
      m_run[rr] = mnew;
      float rs = 0.f;
      bf16x8 pk;
#pragma unroll
      for (int t = 0; t < 8; ++t) {
        const float p = __expf(bl[t] - mnew);
        rs += p;
        pk[t] = (bf16)p;
      }
      *reinterpret_cast<bf16x8*>(srow + swz(row, l * 16)) = pk;
#pragma unroll
      for (int mm = 1; mm < 64; mm <<= 1) rs += __shfl_xor(rs, mm);
      l_run[rr] = l_run[rr] * sc + rs;
      if (l == 0) {
        scl[row] = sc;
        if (c == 1) lred[row] = l_run[rr];
      }
    }
    BAR_LGKM();  // P, scl (and final lred) visible

    // ---- P3: acc = acc*scl + P @ V^T (wave owns d-strip wv*16..+15) ----
    {
      const f32x4 sclv = *reinterpret_cast<const f32x4*>(&scl[q4 * 4]);
      const bf16* vq = vbase + (size_t)(wv * 16 + l16) * NSEQ + c * 512 + q4 * 8;
      char* prow = S_lds + l16 * 1152;
#pragma unroll
      for (int kk = 0; kk < 4; ++kk) acc[kk] *= sclv;
#pragma unroll
      for (int kk = 0; kk < 4; ++kk) {
#pragma unroll
        for (int ki = 0; ki < 4; ++ki) {
          const int ks = kk * 4 + ki;
          const bf16x8 pa = *reinterpret_cast<const bf16x8*>(
              prow + swz(l16, ks * 64 + q4 * 16));
          const bf16x8 vf = *reinterpret_cast<const bf16x8*>(vq + ks * 32);
          acc[kk] = MFMA16(pa, vf, acc[kk]);
        }
      }
    }
    if (c == 0) BAR_LGKM();  // S_lds free for next chunk's P1
  }

  // ---- epilogue: normalize, write attn_out ----
  const f32x4 lv = *reinterpret_cast<const f32x4*>(&lred[q4 * 4]);
  const f32x4 af = (acc[0] + acc[1]) + (acc[2] + acc[3]);
  const int b = bh / NHEADS, head = bh % NHEADS;
#pragma unroll
  for (int r = 0; r < 4; ++r) {
    const int q = q4 * 4 + r;
    attn_out[((size_t)b * NSEQ + i0 + q) * DIMM + head * DH + wv * 16 + l16] =
        (bf16)(af[r] / lv[r]);
  }
}

// -------- output projection: attn_out(8192x768) @ woutT + b_out -> f32 out --------
__global__ __launch_bounds__(256) void oproj_gemm(
    const bf16* __restrict__ ain, const bf16* __restrict__ wT,
    const float* __restrict__ bias, float* __restrict__ out) {
  __shared__ __align__(16) bf16 As[128 * 32];
  __shared__ __align__(16) bf16 Bs[64 * 32];
  const int tid = threadIdx.x;
  const int wv = tid >> 6, l = tid & 63;
  const int l16 = l & 15, q4 = l >> 4;
  const int c0 = blockIdx.x * 64, row0 = blockIdx.y * 128;
  const int sr = tid >> 2, skk = (tid & 3) * 8;
  f32x4 acc0[4], acc1[4];
#pragma unroll
  for (int c = 0; c < 4; ++c) {
    acc0[c] = f32x4{0.f, 0.f, 0.f, 0.f};
    acc1[c] = f32x4{0.f, 0.f, 0.f, 0.f};
  }
  for (int k0 = 0; k0 < DIMM; k0 += 32) {
    __syncthreads();
    load_lds16(ain + (size_t)(row0 + sr) * DIMM + k0 + skk, As + tid * 8);
    load_lds16(ain + (size_t)(row0 + 64 + sr) * DIMM + k0 + skk, As + 2048 + tid * 8);
    load_lds16(wT + (size_t)(c0 + sr) * DIMM + k0 + skk, Bs + tid * 8);
    __syncthreads();
    const bf16x8 a0 = *reinterpret_cast<const bf16x8*>(&As[(wv * 32 + l16) * 32 + q4 * 8]);
    const bf16x8 a1 = *reinterpret_cast<const bf16x8*>(&As[(wv * 32 + 16 + l16) * 32 + q4 * 8]);
#pragma unroll
    for (int c = 0; c < 4; ++c) {
      const bf16x8 bb = *reinterpret_cast<const bf16x8*>(&Bs[(c * 16 + l16) * 32 + q4 * 8]);
      acc0[c] = MFMA16(a0, bb, acc0[c]);
      acc1[c] = MFMA16(a1, bb, acc1[c]);
    }
  }
#pragma unroll
  for (int c = 0; c < 4; ++c) {
    const int gc = c0 + c * 16 + l16;
    const float bv = bias[gc];
#pragma unroll
    for (int r = 0; r < 4; ++r) {
      out[(size_t)(row0 + wv * 32 + q4 * 4 + r) * DIMM + gc] = acc0[c][r] + bv;
      out[(size_t)(row0 + wv * 32 + 16 + q4 * 4 + r) * DIMM + gc] = acc1[c][r] + bv;
    }
  }
}

extern "C" void kernel_launch(void* const* d_in, const int* in_sizes, int n_in,
                              void* d_out, int out_size, void* d_ws, size_t ws_size,
                              hipStream_t stream) {
  const float* x = (const float*)d_in[0];
  const float* h = (const float*)d_in[1];
  const float* gamma = (const float*)d_in[2];
  const float* beta = (const float*)d_in[3];
  const float* w_qkv = (const float*)d_in[4];
  const float* w_out = (const float*)d_in[5];
  const float* b_out = (const float*)d_in[6];
  float* out = (float*)d_out;
  float* blended = out + (size_t)NB * NSEQ * DIMM;

  char* ws = (char*)d_ws;
  bf16* xn = (bf16*)(ws);                   // 12.6 MB; reused as attn_out after qkv_gemm
  bf16* qb = (bf16*)(ws + 12582912);
  bf16* kb = (bf16*)(ws + 25165824);
  bf16* vt = (bf16*)(ws + 37748736);
  bf16* wqkvT = (bf16*)(ws + 50331648);
  bf16* woutT = (bf16*)(ws + 53870592);

  hipLaunchKernelGGL(ln_kernel, dim3(2048), dim3(256), 0, stream, x, gamma, beta, xn);
  hipLaunchKernelGGL(tcast_kernel, dim3(72, 24), dim3(256), 0, stream, w_qkv, wqkvT, DIMM, NQKV);
  hipLaunchKernelGGL(tcast_kernel, dim3(24, 24), dim3(256), 0, stream, w_out, woutT, DIMM, DIMM);
  hipLaunchKernelGGL(qkv_gemm, dim3(36, 64), dim3(256), 0, stream, xn, wqkvT, qb, kb, vt);
  hipLaunchKernelGGL(attn_kernel, dim3(64, 96), dim3(256), 0, stream, qb, kb, vt, h, blended, xn);
  hipLaunchKernelGGL(oproj_gemm, dim3(12, 64), dim3(256), 0, stream, xn, woutT, b_out, out);
}

// Round 12
// 413.224 us; speedup vs baseline: 1.3186x; 1.3186x over previous
//
#include <hip/hip_runtime.h>
#include <hip/hip_bf16.h>
#include <stdint.h>

#define NB 8
#define NSEQ 1024
#define DIMM 768
#define NHEADS 12
#define DH 64
#define NQKV 2304
#define ALPHA_ 0.25f
#define SCALE_ 0.125f
#define EPS_ 1e-5f

typedef __bf16 bf16;
typedef bf16 bf16x8 __attribute__((ext_vector_type(8)));
typedef bf16 bf16x4 __attribute__((ext_vector_type(4)));
typedef float f32x4 __attribute__((ext_vector_type(4)));

#define MFMA16(a, b, c) __builtin_amdgcn_mfma_f32_16x16x32_bf16((a), (b), (c), 0, 0, 0)

static __device__ __forceinline__ void load_lds16(const void* gsrc, void* ldst) {
  __builtin_amdgcn_global_load_lds(
      (__attribute__((address_space(1))) void*)gsrc,
      (__attribute__((address_space(3))) void*)ldst, 16, 0, 0);
}

// lgkm-only barrier (in-flight global loads ride across)
#define BAR_LGKM()                                             \
  do {                                                         \
    __builtin_amdgcn_sched_barrier(0);                         \
    asm volatile("s_waitcnt lgkmcnt(0)" ::: "memory");         \
    __builtin_amdgcn_s_barrier();                              \
    __builtin_amdgcn_sched_barrier(0);                         \
  } while (0)

// LDS byte-offset swizzle (row stride ==0 mod 128B): XOR bits[6:4] with
// (row&7) ^ colbyte bits[9:7]. Preserves 16B alignment.
static __device__ __forceinline__ int swz(int row, int cb) {
  return cb ^ ((((row & 7) ^ ((cb >> 7) & 7)) << 4));
}

// ---------------- LayerNorm + bf16 cast: x(8192x768) -> xn bf16 ----------------
__global__ __launch_bounds__(256) void ln_kernel(
    const float* __restrict__ x, const float* __restrict__ gamma,
    const float* __restrict__ beta, bf16* __restrict__ xn) {
  const int row = blockIdx.x * 4 + (threadIdx.x >> 6);
  const int lane = threadIdx.x & 63;
  const float* xr = x + (size_t)row * DIMM;
  float4 v[3];
  float s = 0.f, s2 = 0.f;
#pragma unroll
  for (int c = 0; c < 3; ++c) {
    v[c] = *reinterpret_cast<const float4*>(xr + c * 256 + lane * 4);
    s += v[c].x + v[c].y + v[c].z + v[c].w;
    s2 += v[c].x * v[c].x + v[c].y * v[c].y + v[c].z * v[c].z + v[c].w * v[c].w;
  }
#pragma unroll
  for (int m = 1; m < 64; m <<= 1) {
    s += __shfl_xor(s, m);
    s2 += __shfl_xor(s2, m);
  }
  const float mu = s * (1.f / DIMM);
  const float rstd = rsqrtf(s2 * (1.f / DIMM) - mu * mu + EPS_);
#pragma unroll
  for (int c = 0; c < 3; ++c) {
    const float4 g4 = *reinterpret_cast<const float4*>(gamma + c * 256 + lane * 4);
    const float4 b4 = *reinterpret_cast<const float4*>(beta + c * 256 + lane * 4);
    bf16x4 o;
    o[0] = (bf16)((v[c].x - mu) * rstd * g4.x + b4.x);
    o[1] = (bf16)((v[c].y - mu) * rstd * g4.y + b4.y);
    o[2] = (bf16)((v[c].z - mu) * rstd * g4.z + b4.z);
    o[3] = (bf16)((v[c].w - mu) * rstd * g4.w + b4.w);
    *reinterpret_cast<bf16x4*>(xn + (size_t)row * DIMM + c * 256 + lane * 4) = o;
  }
}

// ------------- transpose + cast: f32 in[R][C] -> bf16 out[C][R] -------------
__global__ __launch_bounds__(256) void tcast_kernel(
    const float* __restrict__ in, bf16* __restrict__ out, int R, int C) {
  __shared__ float tile[32][33];
  const int tx = threadIdx.x & 31, ty = threadIdx.x >> 5;
  const int c0 = blockIdx.x * 32, r0 = blockIdx.y * 32;
#pragma unroll
  for (int i = ty; i < 32; i += 8)
    tile[i][tx] = in[(size_t)(r0 + i) * C + c0 + tx];
  __syncthreads();
#pragma unroll
  for (int i = ty; i < 32; i += 8)
    out[(size_t)(c0 + i) * R + r0 + tx] = (bf16)tile[tx][i];
}

// -------- QKV GEMM: xn(8192x768) @ wT(2304 cols x 768 k) -> q,k,vT bf16 --------
__global__ __launch_bounds__(256) void qkv_gemm(
    const bf16* __restrict__ xn, const bf16* __restrict__ wT,
    bf16* __restrict__ qb, bf16* __restrict__ kb, bf16* __restrict__ vt) {
  __shared__ __align__(16) bf16 As[128 * 32];
  __shared__ __align__(16) bf16 Bs[64 * 32];
  const int tid = threadIdx.x;
  const int wv = tid >> 6, l = tid & 63;
  const int l16 = l & 15, q4 = l >> 4;
  const int c0 = blockIdx.x * 64, row0 = blockIdx.y * 128;
  const int sr = tid >> 2, skk = (tid & 3) * 8;
  f32x4 acc0[4], acc1[4];
#pragma unroll
  for (int c = 0; c < 4; ++c) {
    acc0[c] = f32x4{0.f, 0.f, 0.f, 0.f};
    acc1[c] = f32x4{0.f, 0.f, 0.f, 0.f};
  }
  for (int k0 = 0; k0 < DIMM; k0 += 32) {
    __syncthreads();
    load_lds16(xn + (size_t)(row0 + sr) * DIMM + k0 + skk, As + tid * 8);
    load_lds16(xn + (size_t)(row0 + 64 + sr) * DIMM + k0 + skk, As + 2048 + tid * 8);
    load_lds16(wT + (size_t)(c0 + sr) * DIMM + k0 + skk, Bs + tid * 8);
    __syncthreads();
    const bf16x8 a0 = *reinterpret_cast<const bf16x8*>(&As[(wv * 32 + l16) * 32 + q4 * 8]);
    const bf16x8 a1 = *reinterpret_cast<const bf16x8*>(&As[(wv * 32 + 16 + l16) * 32 + q4 * 8]);
#pragma unroll
    for (int c = 0; c < 4; ++c) {
      const bf16x8 bb = *reinterpret_cast<const bf16x8*>(&Bs[(c * 16 + l16) * 32 + q4 * 8]);
      acc0[c] = MFMA16(a0, bb, acc0[c]);
      acc1[c] = MFMA16(a1, bb, acc1[c]);
    }
  }
  const int sect = c0 / DIMM;          // 0=q 1=k 2=v (uniform per block)
  const int head = (c0 % DIMM) >> 6;   // uniform per block
#pragma unroll
  for (int c = 0; c < 4; ++c) {
    const int dd = c * 16 + l16;
#pragma unroll
    for (int r = 0; r < 4; ++r) {
#pragma unroll
      for (int rsub = 0; rsub < 2; ++rsub) {
        const int gm = row0 + wv * 32 + rsub * 16 + q4 * 4 + r;
        const int b = gm >> 10, n = gm & 1023;
        const size_t bhh = (size_t)b * NHEADS + head;
        const float av = rsub ? acc1[c][r] : acc0[c][r];
        const bf16 val = (bf16)av;
        if (sect == 0)      qb[(bhh * NSEQ + n) * DH + dd] = val;
        else if (sect == 1) kb[(bhh * NSEQ + n) * DH + dd] = val;
        else                vt[(bhh * DH + dd) * NSEQ + n] = val;
      }
    }
  }
}

// -------- fused attention: two-tile software pipeline (A,B same bh) --------
// Block: 32 q-rows = 2 tiles of 16; j in 2 chunks of 512, online rescale.
// Steady-state phases pair one tile's streaming P2 with the other tile's
// MFMA phase (P1/P3), so each wave issues memory ~2/3 of the time while
// MFMA covers latency. K/V shared between tiles (same bh) -> L2 reuse.
// launch_bounds(256,3): VGPR budget 168 -> no spill possible (R9/R11 lesson).
__global__ __launch_bounds__(256, 3) void attn_kernel(
    const bf16* __restrict__ qb, const bf16* __restrict__ kb,
    const bf16* __restrict__ vt, const float* __restrict__ h,
    float* __restrict__ blended, bf16* __restrict__ attn_out) {
  __shared__ __align__(16) char S_lds[2 * 16 * 1152];  // 36,864 B (2 tile regions)
  __shared__ __align__(16) float scl[2][16];
  __shared__ __align__(16) float lred[2][16];

  const int tid = threadIdx.x;
  const int wv = tid >> 6, l = tid & 63;
  const int l16 = l & 15, q4 = l >> 4;
  const int i0 = blockIdx.x * 32;
  const int bh = blockIdx.y;

  const float* hbase = h + ((size_t)bh << 20);
  float* bbase = blended + ((size_t)bh << 20);
  const bf16* kbase = kb + (size_t)bh * NSEQ * DH;
  const bf16* vbase = vt + (size_t)bh * DH * NSEQ;

  bf16x8 qTA[2], qTB[2];
#pragma unroll
  for (int w2 = 0; w2 < 2; ++w2) {
    qTA[w2] = *reinterpret_cast<const bf16x8*>(
        qb + ((size_t)bh * NSEQ + i0 + l16) * DH + w2 * 32 + q4 * 8);
    qTB[w2] = *reinterpret_cast<const bf16x8*>(
        qb + ((size_t)bh * NSEQ + i0 + 16 + l16) * DH + w2 * 32 + q4 * 8);
  }

  f32x4 accA[4], accB[4];
  float mA[4], lA[4], mB[4], lB[4];
#pragma unroll
  for (int k = 0; k < 4; ++k) {
    accA[k] = f32x4{0.f, 0.f, 0.f, 0.f};
    accB[k] = f32x4{0.f, 0.f, 0.f, 0.f};
    mA[k] = -1e30f; lA[k] = 0.f; mB[k] = -1e30f; lB[k] = 0.f;
  }

  // ---- P1: S(tile t, chunk c) = QK^T -> swizzled LDS region t ----
  auto P1 = [&](int t, int c, const bf16x8 (&qT)[2]) {
    const bf16* kq = kbase + (size_t)(c * 512 + wv * 128 + l16) * DH + q4 * 8;
    char* srow_w = S_lds + t * 18432 + l16 * 1152;
#pragma unroll
    for (int st = 0; st < 2; ++st) {
      f32x4 s[4];
#pragma unroll
      for (int js = 0; js < 4; ++js) s[js] = f32x4{0.f, 0.f, 0.f, 0.f};
#pragma unroll
      for (int js = 0; js < 4; ++js) {
#pragma unroll
        for (int w2 = 0; w2 < 2; ++w2) {
          const bf16x8 kf = *reinterpret_cast<const bf16x8*>(
              kq + (size_t)(st * 64 + js * 16) * DH + w2 * 32);
          s[js] = MFMA16(kf, qT[w2], s[js]);
        }
      }
#pragma unroll
      for (int js = 0; js < 4; ++js) {
        bf16x4 pk;
#pragma unroll
        for (int r = 0; r < 4; ++r) pk[r] = (bf16)(s[js][r] * (ALPHA_ * SCALE_));
        const int cb = (wv * 256 + st * 128 + js * 32 + q4 * 8);
        *reinterpret_cast<bf16x4*>(srow_w + swz(l16, cb)) = pk;
      }
    }
  };

  // ---- P2: stream tile t's 4 rows of chunk c; online softmax; P->LDS ----
  auto P2 = [&](int t, int c, float (&m_run)[4], float (&l_run)[4]) {
    char* sreg = S_lds + t * 18432;
    const int gi0 = i0 + t * 16;
#pragma unroll
    for (int rr = 0; rr < 4; ++rr) {
      const int row = wv * 4 + rr;
      char* srow = sreg + row * 1152;
      const bf16x8 sv = *reinterpret_cast<const bf16x8*>(srow + swz(row, l * 16));
      const float* hp = hbase + (size_t)(gi0 + row) * NSEQ + c * 512 + l * 8;
      const f32x4 h0 = *reinterpret_cast<const f32x4*>(hp);
      const f32x4 h1 = *reinterpret_cast<const f32x4*>(hp + 4);
      float bl[8];
#pragma unroll
      for (int u = 0; u < 4; ++u) bl[u] = fmaf(0.75f, h0[u], (float)sv[u]);
#pragma unroll
      for (int u = 0; u < 4; ++u) bl[4 + u] = fmaf(0.75f, h1[u], (float)sv[4 + u]);
      float* bp = bbase + (size_t)(gi0 + row) * NSEQ + c * 512 + l * 8;
      f32x4 b0, b1;
#pragma unroll
      for (int u = 0; u < 4; ++u) { b0[u] = bl[u]; b1[u] = bl[4 + u]; }
      *reinterpret_cast<f32x4*>(bp) = b0;
      *reinterpret_cast<f32x4*>(bp + 4) = b1;
      float tm = bl[0];
#pragma unroll
      for (int u = 1; u < 8; ++u) tm = fmaxf(tm, bl[u]);
#pragma unroll
      for (int mm = 1; mm < 64; mm <<= 1) tm = fmaxf(tm, __shfl_xor(tm, mm));
      const float mnew = fmaxf(m_run[rr], tm);
      const float sc = __expf(m_run[rr] - mnew);
      m_run[rr] = mnew;
      float rs = 0.f;
      bf16x8 pk;
#pragma unroll
      for (int u = 0; u < 8; ++u) {
        const float p = __expf(bl[u] - mnew);
        rs += p;
        pk[u] = (bf16)p;
      }
      *reinterpret_cast<bf16x8*>(srow + swz(row, l * 16)) = pk;
#pragma unroll
      for (int mm = 1; mm < 64; mm <<= 1) rs += __shfl_xor(rs, mm);
      l_run[rr] = l_run[rr] * sc + rs;
      if (l == 0) {
        scl[t][row] = sc;
        if (c == 1) lred[t][row] = l_run[rr];
      }
    }
  };

  // ---- P3: acc = acc*scl + P(tile t, chunk c) @ V^T ----
  auto P3 = [&](int t, int c, f32x4 (&acc)[4]) {
    const f32x4 sclv = *reinterpret_cast<const f32x4*>(&scl[t][q4 * 4]);
    const bf16* vq = vbase + (size_t)(wv * 16 + l16) * NSEQ + c * 512 + q4 * 8;
    char* prow = S_lds + t * 18432 + l16 * 1152;
#pragma unroll
    for (int kk = 0; kk < 4; ++kk) acc[kk] *= sclv;
#pragma unroll
    for (int kk = 0; kk < 4; ++kk) {
#pragma unroll
      for (int ki = 0; ki < 4; ++ki) {
        const int ks = kk * 4 + ki;
        const bf16x8 pa = *reinterpret_cast<const bf16x8*>(
            prow + swz(l16, ks * 64 + q4 * 16));
        const bf16x8 vf = *reinterpret_cast<const bf16x8*>(vq + ks * 32);
        acc[kk] = MFMA16(pa, vf, acc[kk]);
      }
    }
  };

  // ---- software pipeline over (tile, phase, chunk) ----
  P1(0, 0, qTA);
  BAR_LGKM();
  P2(0, 0, mA, lA);  P1(1, 0, qTB);
  BAR_LGKM();
  P2(1, 0, mB, lB);  P3(0, 0, accA);
  BAR_LGKM();
  P1(0, 1, qTA);     P3(1, 0, accB);
  BAR_LGKM();
  P2(0, 1, mA, lA);  P1(1, 1, qTB);
  BAR_LGKM();
  P2(1, 1, mB, lB);  P3(0, 1, accA);
  BAR_LGKM();
  P3(1, 1, accB);

  // ---- epilogue: normalize, write attn_out (both tiles) ----
  const int b = bh / NHEADS, head = bh % NHEADS;
  {
    const f32x4 lv = *reinterpret_cast<const f32x4*>(&lred[0][q4 * 4]);
    const f32x4 af = (accA[0] + accA[1]) + (accA[2] + accA[3]);
#pragma unroll
    for (int r = 0; r < 4; ++r) {
      const int q = q4 * 4 + r;
      attn_out[((size_t)b * NSEQ + i0 + q) * DIMM + head * DH + wv * 16 + l16] =
          (bf16)(af[r] / lv[r]);
    }
  }
  {
    const f32x4 lv = *reinterpret_cast<const f32x4*>(&lred[1][q4 * 4]);
    const f32x4 af = (accB[0] + accB[1]) + (accB[2] + accB[3]);
#pragma unroll
    for (int r = 0; r < 4; ++r) {
      const int q = q4 * 4 + r;
      attn_out[((size_t)b * NSEQ + i0 + 16 + q) * DIMM + head * DH + wv * 16 + l16] =
          (bf16)(af[r] / lv[r]);
    }
  }
}

// -------- output projection: attn_out(8192x768) @ woutT + b_out -> f32 out --------
__global__ __launch_bounds__(256) void oproj_gemm(
    const bf16* __restrict__ ain, const bf16* __restrict__ wT,
    const float* __restrict__ bias, float* __restrict__ out) {
  __shared__ __align__(16) bf16 As[128 * 32];
  __shared__ __align__(16) bf16 Bs[64 * 32];
  const int tid = threadIdx.x;
  const int wv = tid >> 6, l = tid & 63;
  const int l16 = l & 15, q4 = l >> 4;
  const int c0 = blockIdx.x * 64, row0 = blockIdx.y * 128;
  const int sr = tid >> 2, skk = (tid & 3) * 8;
  f32x4 acc0[4], acc1[4];
#pragma unroll
  for (int c = 0; c < 4; ++c) {
    acc0[c] = f32x4{0.f, 0.f, 0.f, 0.f};
    acc1[c] = f32x4{0.f, 0.f, 0.f, 0.f};
  }
  for (int k0 = 0; k0 < DIMM; k0 += 32) {
    __syncthreads();
    load_lds16(ain + (size_t)(row0 + sr) * DIMM + k0 + skk, As + tid * 8);
    load_lds16(ain + (size_t)(row0 + 64 + sr) * DIMM + k0 + skk, As + 2048 + tid * 8);
    load_lds16(wT + (size_t)(c0 + sr) * DIMM + k0 + skk, Bs + tid * 8);
    __syncthreads();
    const bf16x8 a0 = *reinterpret_cast<const bf16x8*>(&As[(wv * 32 + l16) * 32 + q4 * 8]);
    const bf16x8 a1 = *reinterpret_cast<const bf16x8*>(&As[(wv * 32 + 16 + l16) * 32 + q4 * 8]);
#pragma unroll
    for (int c = 0; c < 4; ++c) {
      const bf16x8 bb = *reinterpret_cast<const bf16x8*>(&Bs[(c * 16 + l16) * 32 + q4 * 8]);
      acc0[c] = MFMA16(a0, bb, acc0[c]);
      acc1[c] = MFMA16(a1, bb, acc1[c]);
    }
  }
#pragma unroll
  for (int c = 0; c < 4; ++c) {
    const int gc = c0 + c * 16 + l16;
    const float bv = bias[gc];
#pragma unroll
    for (int r = 0; r < 4; ++r) {
      out[(size_t)(row0 + wv * 32 + q4 * 4 + r) * DIMM + gc] = acc0[c][r] + bv;
      out[(size_t)(row0 + wv * 32 + 16 + q4 * 4 + r) * DIMM + gc] = acc1[c][r] + bv;
    }
  }
}

extern "C" void kernel_launch(void* const* d_in, const int* in_sizes, int n_in,
                              void* d_out, int out_size, void* d_ws, size_t ws_size,
                              hipStream_t stream) {
  const float* x = (const float*)d_in[0];
  const float* h = (const float*)d_in[1];
  const float* gamma = (const float*)d_in[2];
  const float* beta = (const float*)d_in[3];
  const float* w_qkv = (const float*)d_in[4];
  const float* w_out = (const float*)d_in[5];
  const float* b_out = (const float*)d_in[6];
  float* out = (float*)d_out;
  float* blended = out + (size_t)NB * NSEQ * DIMM;

  char* ws = (char*)d_ws;
  bf16* xn = (bf16*)(ws);                   // 12.6 MB; reused as attn_out after qkv_gemm
  bf16* qb = (bf16*)(ws + 12582912);
  bf16* kb = (bf16*)(ws + 25165824);
  bf16* vt = (bf16*)(ws + 37748736);
  bf16* wqkvT = (bf16*)(ws + 50331648);
  bf16* woutT = (bf16*)(ws + 53870592);

  hipLaunchKernelGGL(ln_kernel, dim3(2048), dim3(256), 0, stream, x, gamma, beta, xn);
  hipLaunchKernelGGL(tcast_kernel, dim3(72, 24), dim3(256), 0, stream, w_qkv, wqkvT, DIMM, NQKV);
  hipLaunchKernelGGL(tcast_kernel, dim3(24, 24), dim3(256), 0, stream, w_out, woutT, DIMM, DIMM);
  hipLaunchKernelGGL(qkv_gemm, dim3(36, 64), dim3(256), 0, stream, xn, wqkvT, qb, kb, vt);
  hipLaunchKernelGGL(attn_kernel, dim3(32, 96), dim3(256), 0, stream, qb, kb, vt, h, blended, xn);
  hipLaunchKernelGGL(oproj_gemm, dim3(12, 64), dim3(256), 0, stream, xn, woutT, b_out, out);
}

// Round 13
// 388.025 us; speedup vs baseline: 1.4042x; 1.0649x over previous
//
#include <hip/hip_runtime.h>
#include <hip/hip_bf16.h>
#include <stdint.h>

#define NB 8
#define NSEQ 1024
#define DIMM 768
#define NHEADS 12
#define DH 64
#define NQKV 2304
#define ALPHA_ 0.25f
#define SCALE_ 0.125f
#define EPS_ 1e-5f

typedef __bf16 bf16;
typedef bf16 bf16x8 __attribute__((ext_vector_type(8)));
typedef bf16 bf16x4 __attribute__((ext_vector_type(4)));
typedef float f32x4 __attribute__((ext_vector_type(4)));

#define MFMA16(a, b, c) __builtin_amdgcn_mfma_f32_16x16x32_bf16((a), (b), (c), 0, 0, 0)

static __device__ __forceinline__ void load_lds16(const void* gsrc, void* ldst) {
  __builtin_amdgcn_global_load_lds(
      (__attribute__((address_space(1))) void*)gsrc,
      (__attribute__((address_space(3))) void*)ldst, 16, 0, 0);
}

// lgkm-only barrier (in-flight global loads ride across)
#define BAR_LGKM()                                             \
  do {                                                         \
    __builtin_amdgcn_sched_barrier(0);                         \
    asm volatile("s_waitcnt lgkmcnt(0)" ::: "memory");         \
    __builtin_amdgcn_s_barrier();                              \
    __builtin_amdgcn_sched_barrier(0);                         \
  } while (0)

// LDS byte-offset swizzle: XOR bits[6:4] with (row&7) ^ colbyte bits[9:7].
static __device__ __forceinline__ int swz(int row, int cb) {
  return cb ^ ((((row & 7) ^ ((cb >> 7) & 7)) << 4));
}

// ---------------- LayerNorm + bf16 cast: x(8192x768) -> xn bf16 ----------------
__global__ __launch_bounds__(256) void ln_kernel(
    const float* __restrict__ x, const float* __restrict__ gamma,
    const float* __restrict__ beta, bf16* __restrict__ xn) {
  const int row = blockIdx.x * 4 + (threadIdx.x >> 6);
  const int lane = threadIdx.x & 63;
  const float* xr = x + (size_t)row * DIMM;
  float4 v[3];
  float s = 0.f, s2 = 0.f;
#pragma unroll
  for (int c = 0; c < 3; ++c) {
    v[c] = *reinterpret_cast<const float4*>(xr + c * 256 + lane * 4);
    s += v[c].x + v[c].y + v[c].z + v[c].w;
    s2 += v[c].x * v[c].x + v[c].y * v[c].y + v[c].z * v[c].z + v[c].w * v[c].w;
  }
#pragma unroll
  for (int m = 1; m < 64; m <<= 1) {
    s += __shfl_xor(s, m);
    s2 += __shfl_xor(s2, m);
  }
  const float mu = s * (1.f / DIMM);
  const float rstd = rsqrtf(s2 * (1.f / DIMM) - mu * mu + EPS_);
#pragma unroll
  for (int c = 0; c < 3; ++c) {
    const float4 g4 = *reinterpret_cast<const float4*>(gamma + c * 256 + lane * 4);
    const float4 b4 = *reinterpret_cast<const float4*>(beta + c * 256 + lane * 4);
    bf16x4 o;
    o[0] = (bf16)((v[c].x - mu) * rstd * g4.x + b4.x);
    o[1] = (bf16)((v[c].y - mu) * rstd * g4.y + b4.y);
    o[2] = (bf16)((v[c].z - mu) * rstd * g4.z + b4.z);
    o[3] = (bf16)((v[c].w - mu) * rstd * g4.w + b4.w);
    *reinterpret_cast<bf16x4*>(xn + (size_t)row * DIMM + c * 256 + lane * 4) = o;
  }
}

// ------------- transpose + cast: f32 in[R][C] -> bf16 out[C][R] -------------
__global__ __launch_bounds__(256) void tcast_kernel(
    const float* __restrict__ in, bf16* __restrict__ out, int R, int C) {
  __shared__ float tile[32][33];
  const int tx = threadIdx.x & 31, ty = threadIdx.x >> 5;
  const int c0 = blockIdx.x * 32, r0 = blockIdx.y * 32;
#pragma unroll
  for (int i = ty; i < 32; i += 8)
    tile[i][tx] = in[(size_t)(r0 + i) * C + c0 + tx];
  __syncthreads();
#pragma unroll
  for (int i = ty; i < 32; i += 8)
    out[(size_t)(c0 + i) * R + r0 + tx] = (bf16)tile[tx][i];
}

// -- QKV GEMM 128x128: xn(8192x768) @ wT(2304x768 k-major) -> q,k,vT bf16 --
// 4 waves in 2x2; each wave 64x64 out via 4x4 16x16 fragments.
// Per K-step(32): 4x global_load_lds(16B), 8x ds_read_b128, 16x MFMA.
__global__ __launch_bounds__(256) void qkv_gemm(
    const bf16* __restrict__ xn, const bf16* __restrict__ wT,
    bf16* __restrict__ qb, bf16* __restrict__ kb, bf16* __restrict__ vt) {
  __shared__ __align__(16) bf16 As[128 * 32];
  __shared__ __align__(16) bf16 Bs[128 * 32];
  const int tid = threadIdx.x;
  const int wv = tid >> 6, l = tid & 63;
  const int l16 = l & 15, q4 = l >> 4;
  const int wr = wv >> 1, wc = wv & 1;
  const int c0 = blockIdx.x * 128, row0 = blockIdx.y * 128;
  const int sr = tid >> 2, skk = (tid & 3) * 8;
  f32x4 acc[4][4];
#pragma unroll
  for (int m = 0; m < 4; ++m)
#pragma unroll
    for (int n = 0; n < 4; ++n) acc[m][n] = f32x4{0.f, 0.f, 0.f, 0.f};
  for (int k0 = 0; k0 < DIMM; k0 += 32) {
    __syncthreads();
    load_lds16(xn + (size_t)(row0 + sr) * DIMM + k0 + skk, As + tid * 8);
    load_lds16(xn + (size_t)(row0 + 64 + sr) * DIMM + k0 + skk, As + 2048 + tid * 8);
    load_lds16(wT + (size_t)(c0 + sr) * DIMM + k0 + skk, Bs + tid * 8);
    load_lds16(wT + (size_t)(c0 + 64 + sr) * DIMM + k0 + skk, Bs + 2048 + tid * 8);
    __syncthreads();
    bf16x8 a[4], b[4];
#pragma unroll
    for (int m = 0; m < 4; ++m)
      a[m] = *reinterpret_cast<const bf16x8*>(&As[(wr * 64 + m * 16 + l16) * 32 + q4 * 8]);
#pragma unroll
    for (int n = 0; n < 4; ++n)
      b[n] = *reinterpret_cast<const bf16x8*>(&Bs[(wc * 64 + n * 16 + l16) * 32 + q4 * 8]);
#pragma unroll
    for (int m = 0; m < 4; ++m)
#pragma unroll
      for (int n = 0; n < 4; ++n) acc[m][n] = MFMA16(a[m], b[n], acc[m][n]);
  }
  const int sect = c0 / DIMM;  // uniform per block (768 = 6*128)
#pragma unroll
  for (int n = 0; n < 4; ++n) {
    const int gc = c0 + wc * 64 + n * 16 + l16;
    const int head = (gc % DIMM) >> 6;
    const int dd = gc & 63;
#pragma unroll
    for (int m = 0; m < 4; ++m) {
#pragma unroll
      for (int r = 0; r < 4; ++r) {
        const int gm = row0 + wr * 64 + m * 16 + q4 * 4 + r;
        const int b_ = gm >> 10, nn = gm & 1023;
        const size_t bhh = (size_t)b_ * NHEADS + head;
        const bf16 val = (bf16)acc[m][n][r];
        if (sect == 0)      qb[(bhh * NSEQ + nn) * DH + dd] = val;
        else if (sect == 1) kb[(bhh * NSEQ + nn) * DH + dd] = val;
        else                vt[(bhh * DH + dd) * NSEQ + nn] = val;
      }
    }
  }
}

// -------- fused attention (exact R7 best config: 290 us measured) --------
// 3-phase: P1 S=QK^T (swapped operands) -> bf16 swizzled LDS [16][1088];
// P2 wave owns 4 full rows: h read / blended write in contiguous 1KB bursts,
// EXACT per-row softmax; P overwrites S. P3 PV from LDS x V^T (L2).
__global__ __launch_bounds__(256, 4) void attn_kernel(
    const bf16* __restrict__ qb, const bf16* __restrict__ kb,
    const bf16* __restrict__ vt, const float* __restrict__ h,
    float* __restrict__ blended, bf16* __restrict__ attn_out) {
  __shared__ __align__(16) char S_lds[16 * 2176];  // bf16 [16][1088], swizzled
  __shared__ float lred[16];

  const int tid = threadIdx.x;
  const int wv = tid >> 6, l = tid & 63;
  const int l16 = l & 15, q4 = l >> 4;
  const int i0 = blockIdx.x * 16;
  const int bh = blockIdx.y;
  const int jb = wv * 256;

  const float* hbase = h + ((size_t)bh << 20);
  float* bbase = blended + ((size_t)bh << 20);

  bf16x8 qT[2];
#pragma unroll
  for (int w2 = 0; w2 < 2; ++w2)
    qT[w2] = *reinterpret_cast<const bf16x8*>(
        qb + ((size_t)bh * NSEQ + i0 + l16) * DH + w2 * 32 + q4 * 8);

  // prefetch h rows wv*4+0,1 (consumed in Phase 2, hidden under Phase 1)
  float4 hv0[4], hv1[4];
#pragma unroll
  for (int t = 0; t < 4; ++t) {
    hv0[t] = *reinterpret_cast<const float4*>(
        hbase + (size_t)(i0 + wv * 4 + 0) * NSEQ + t * 256 + l * 4);
    hv1[t] = *reinterpret_cast<const float4*>(
        hbase + (size_t)(i0 + wv * 4 + 1) * NSEQ + t * 256 + l * 4);
  }

  // ---- Phase 1: S(scaled) -> LDS bf16, swizzled ----
  const bf16* kq = kb + ((size_t)bh * NSEQ + jb + l16) * DH + q4 * 8;
  char* srow_w = S_lds + l16 * 2176;
#pragma unroll
  for (int st = 0; st < 4; ++st) {
    f32x4 s[4];
#pragma unroll
    for (int js = 0; js < 4; ++js) s[js] = f32x4{0.f, 0.f, 0.f, 0.f};
#pragma unroll
    for (int js = 0; js < 4; ++js) {
#pragma unroll
      for (int w2 = 0; w2 < 2; ++w2) {
        const bf16x8 kf = *reinterpret_cast<const bf16x8*>(
            kq + (size_t)(st * 64 + js * 16) * DH + w2 * 32);
        s[js] = MFMA16(kf, qT[w2], s[js]);
      }
    }
#pragma unroll
    for (int js = 0; js < 4; ++js) {
      bf16x4 pk;
#pragma unroll
      for (int r = 0; r < 4; ++r) pk[r] = (bf16)(s[js][r] * (ALPHA_ * SCALE_));
      const int cb = (jb + st * 64 + js * 16 + q4 * 4) * 2;
      *reinterpret_cast<bf16x4*>(srow_w + swz(l16, cb)) = pk;
    }
  }

  // prefetch h rows wv*4+2,3 (fly across the barrier; vmcnt is per-wave)
  float4 hv2[4], hv3[4];
#pragma unroll
  for (int t = 0; t < 4; ++t) {
    hv2[t] = *reinterpret_cast<const float4*>(
        hbase + (size_t)(i0 + wv * 4 + 2) * NSEQ + t * 256 + l * 4);
    hv3[t] = *reinterpret_cast<const float4*>(
        hbase + (size_t)(i0 + wv * 4 + 3) * NSEQ + t * 256 + l * 4);
  }

  BAR_LGKM();  // all waves' S writes visible

  // ---- Phase 2: stream 4 full rows; exact softmax; P overwrites S ----
  auto ROW = [&](int rr, float4* hv) {
    const int row = wv * 4 + rr;
    char* srow = S_lds + row * 2176;
    bf16x4 sv[4];
#pragma unroll
    for (int t = 0; t < 4; ++t)
      sv[t] = *reinterpret_cast<const bf16x4*>(srow + swz(row, t * 512 + l * 8));
    float4 bl[4];
    float tm = -1e30f;
#pragma unroll
    for (int t = 0; t < 4; ++t) {
      bl[t].x = fmaf(0.75f, hv[t].x, (float)sv[t][0]);
      bl[t].y = fmaf(0.75f, hv[t].y, (float)sv[t][1]);
      bl[t].z = fmaf(0.75f, hv[t].z, (float)sv[t][2]);
      bl[t].w = fmaf(0.75f, hv[t].w, (float)sv[t][3]);
      *reinterpret_cast<float4*>(
          bbase + (size_t)(i0 + row) * NSEQ + t * 256 + l * 4) = bl[t];
      tm = fmaxf(tm, fmaxf(fmaxf(bl[t].x, bl[t].y), fmaxf(bl[t].z, bl[t].w)));
    }
#pragma unroll
    for (int mm = 1; mm < 64; mm <<= 1) tm = fmaxf(tm, __shfl_xor(tm, mm));
    float rs = 0.f;
#pragma unroll
    for (int t = 0; t < 4; ++t) {
      bf16x4 pk;
      const float p0 = __expf(bl[t].x - tm); rs += p0; pk[0] = (bf16)p0;
      const float p1 = __expf(bl[t].y - tm); rs += p1; pk[1] = (bf16)p1;
      const float p2 = __expf(bl[t].z - tm); rs += p2; pk[2] = (bf16)p2;
      const float p3 = __expf(bl[t].w - tm); rs += p3; pk[3] = (bf16)p3;
      *reinterpret_cast<bf16x4*>(srow + swz(row, t * 512 + l * 8)) = pk;
    }
#pragma unroll
    for (int mm = 1; mm < 64; mm <<= 1) rs += __shfl_xor(rs, mm);
    if (l == 0) lred[row] = rs;
  };
  ROW(0, hv0);
  ROW(1, hv1);
  ROW(2, hv2);
  ROW(3, hv3);

  BAR_LGKM();  // all P + lred visible

  // ---- Phase 3: out(16q x 16d per wave) = P @ V^T ----
  const bf16* vq = vt + ((size_t)bh * DH + wv * 16 + l16) * NSEQ + q4 * 8;
  char* prow = S_lds + l16 * 2176;
  f32x4 a0 = f32x4{0.f, 0.f, 0.f, 0.f}, a1 = a0, a2 = a0, a3 = a0;
#pragma unroll
  for (int ks = 0; ks < 32; ks += 4) {
    const bf16x8 pa0 = *reinterpret_cast<const bf16x8*>(prow + swz(l16, (ks + 0) * 64 + q4 * 16));
    const bf16x8 vf0 = *reinterpret_cast<const bf16x8*>(vq + (ks + 0) * 32);
    a0 = MFMA16(pa0, vf0, a0);
    const bf16x8 pa1 = *reinterpret_cast<const bf16x8*>(prow + swz(l16, (ks + 1) * 64 + q4 * 16));
    const bf16x8 vf1 = *reinterpret_cast<const bf16x8*>(vq + (ks + 1) * 32);
    a1 = MFMA16(pa1, vf1, a1);
    const bf16x8 pa2 = *reinterpret_cast<const bf16x8*>(prow + swz(l16, (ks + 2) * 64 + q4 * 16));
    const bf16x8 vf2 = *reinterpret_cast<const bf16x8*>(vq + (ks + 2) * 32);
    a2 = MFMA16(pa2, vf2, a2);
    const bf16x8 pa3 = *reinterpret_cast<const bf16x8*>(prow + swz(l16, (ks + 3) * 64 + q4 * 16));
    const bf16x8 vf3 = *reinterpret_cast<const bf16x8*>(vq + (ks + 3) * 32);
    a3 = MFMA16(pa3, vf3, a3);
  }
  const f32x4 af = (a0 + a1) + (a2 + a3);
  const int b = bh / NHEADS, head = bh % NHEADS;
#pragma unroll
  for (int r = 0; r < 4; ++r) {
    const int q = q4 * 4 + r;
    attn_out[((size_t)b * NSEQ + i0 + q) * DIMM + head * DH + wv * 16 + l16] =
        (bf16)(af[r] / lred[q]);
  }
}

// -- output projection 128x128: attn_out(8192x768) @ woutT + b_out -> f32 out --
__global__ __launch_bounds__(256) void oproj_gemm(
    const bf16* __restrict__ ain, const bf16* __restrict__ wT,
    const float* __restrict__ bias, float* __restrict__ out) {
  __shared__ __align__(16) bf16 As[128 * 32];
  __shared__ __align__(16) bf16 Bs[128 * 32];
  const int tid = threadIdx.x;
  const int wv = tid >> 6, l = tid & 63;
  const int l16 = l & 15, q4 = l >> 4;
  const int wr = wv >> 1, wc = wv & 1;
  const int c0 = blockIdx.x * 128, row0 = blockIdx.y * 128;
  const int sr = tid >> 2, skk = (tid & 3) * 8;
  f32x4 acc[4][4];
#pragma unroll
  for (int m = 0; m < 4; ++m)
#pragma unroll
    for (int n = 0; n < 4; ++n) acc[m][n] = f32x4{0.f, 0.f, 0.f, 0.f};
  for (int k0 = 0; k0 < DIMM; k0 += 32) {
    __syncthreads();
    load_lds16(ain + (size_t)(row0 + sr) * DIMM + k0 + skk, As + tid * 8);
    load_lds16(ain + (size_t)(row0 + 64 + sr) * DIMM + k0 + skk, As + 2048 + tid * 8);
    load_lds16(wT + (size_t)(c0 + sr) * DIMM + k0 + skk, Bs + tid * 8);
    load_lds16(wT + (size_t)(c0 + 64 + sr) * DIMM + k0 + skk, Bs + 2048 + tid * 8);
    __syncthreads();
    bf16x8 a[4], b[4];
#pragma unroll
    for (int m = 0; m < 4; ++m)
      a[m] = *reinterpret_cast<const bf16x8*>(&As[(wr * 64 + m * 16 + l16) * 32 + q4 * 8]);
#pragma unroll
    for (int n = 0; n < 4; ++n)
      b[n] = *reinterpret_cast<const bf16x8*>(&Bs[(wc * 64 + n * 16 + l16) * 32 + q4 * 8]);
#pragma unroll
    for (int m = 0; m < 4; ++m)
#pragma unroll
      for (int n = 0; n < 4; ++n) acc[m][n] = MFMA16(a[m], b[n], acc[m][n]);
  }
#pragma unroll
  for (int n = 0; n < 4; ++n) {
    const int gc = c0 + wc * 64 + n * 16 + l16;
    const float bv = bias[gc];
#pragma unroll
    for (int m = 0; m < 4; ++m) {
#pragma unroll
      for (int r = 0; r < 4; ++r) {
        const int gm = row0 + wr * 64 + m * 16 + q4 * 4 + r;
        out[(size_t)gm * DIMM + gc] = acc[m][n][r] + bv;
      }
    }
  }
}

extern "C" void kernel_launch(void* const* d_in, const int* in_sizes, int n_in,
                              void* d_out, int out_size, void* d_ws, size_t ws_size,
                              hipStream_t stream) {
  const float* x = (const float*)d_in[0];
  const float* h = (const float*)d_in[1];
  const float* gamma = (const float*)d_in[2];
  const float* beta = (const float*)d_in[3];
  const float* w_qkv = (const float*)d_in[4];
  const float* w_out = (const float*)d_in[5];
  const float* b_out = (const float*)d_in[6];
  float* out = (float*)d_out;
  float* blended = out + (size_t)NB * NSEQ * DIMM;

  char* ws = (char*)d_ws;
  bf16* xn = (bf16*)(ws);                   // 12.6 MB; reused as attn_out after qkv_gemm
  bf16* qb = (bf16*)(ws + 12582912);
  bf16* kb = (bf16*)(ws + 25165824);
  bf16* vt = (bf16*)(ws + 37748736);
  bf16* wqkvT = (bf16*)(ws + 50331648);
  bf16* woutT = (bf16*)(ws + 53870592);

  hipLaunchKernelGGL(ln_kernel, dim3(2048), dim3(256), 0, stream, x, gamma, beta, xn);
  hipLaunchKernelGGL(tcast_kernel, dim3(72, 24), dim3(256), 0, stream, w_qkv, wqkvT, DIMM, NQKV);
  hipLaunchKernelGGL(tcast_kernel, dim3(24, 24), dim3(256), 0, stream, w_out, woutT, DIMM, DIMM);
  hipLaunchKernelGGL(qkv_gemm, dim3(18, 64), dim3(256), 0, stream, xn, wqkvT, qb, kb, vt);
  hipLaunchKernelGGL(attn_kernel, dim3(64, 96), dim3(256), 0, stream, qb, kb, vt, h, blended, xn);
  hipLaunchKernelGGL(oproj_gemm, dim3(6, 64), dim3(256), 0, stream, xn, woutT, b_out, out);
}